// Round 1
// baseline (419.680 us; speedup 1.0000x reference)
//
#include <hip/hip_runtime.h>
#include <cstddef>

#define B_ 2
#define C_ 32
#define CP 33   // C+1 output channels
#define W_ 256
#define H_ 256
#define X_ 512
#define Y_ 512
#define TX 32   // x-tile per block

// ws layout (floats):
//   wlon: [B][W][X]   = 262144
//   wlat: [B][H][Y]   = 262144
//   ee0 : [B][X][Y]   = 524288
// total 1,048,576 floats = 4 MB

// ---------------- RBF weight tables ----------------
__global__ __launch_bounds__(256) void rbf_kernel(
    const float* __restrict__ xin_lon, const float* __restrict__ xin_lat,
    const float* __restrict__ xout_lon, const float* __restrict__ xout_lat,
    const float* __restrict__ init_ls,
    float* __restrict__ wlon, float* __restrict__ wlat)
{
    int idx = blockIdx.x * 256 + threadIdx.x;
    float ls = init_ls[0];
    float cc = -0.5f / (ls * ls);
    const int nlon = B_ * W_ * X_;
    const int nlat = B_ * H_ * Y_;
    if (idx < nlon) {
        int b = idx / (W_ * X_);
        int r = idx - b * (W_ * X_);
        int w = r >> 9;          // / X_
        int x = r & (X_ - 1);
        float d = xin_lon[b * W_ + w] - xout_lon[b * X_ + x];
        wlon[idx] = __expf(cc * d * d);
    } else {
        int j = idx - nlon;
        if (j < nlat) {
            int b = j / (H_ * Y_);
            int r = j - b * (H_ * Y_);
            int h = r >> 9;      // / Y_
            int y = r & (Y_ - 1);
            float d = xin_lat[b * H_ + h] - xout_lat[b * Y_ + y];
            wlat[j] = __expf(cc * d * d);
        }
    }
}

// ---------------- density channel: ee0 = dens x wlon x wlat ----------------
// grid: B * (X/TX=16) * (Y/128=4) = 128 blocks, 256 threads
__global__ __launch_bounds__(256) void dens_kernel(
    const float* __restrict__ wt, const float* __restrict__ wlon,
    const float* __restrict__ wlat, float* __restrict__ ee0,
    float* __restrict__ out)
{
    __shared__ float lonT[W_][TX];   // 32 KB
    __shared__ float Tt[H_][TX];     // 32 KB
    const int bid = blockIdx.x;
    const int b   = bid >> 6;
    const int rem = bid & 63;
    const int xt  = rem >> 2;        // 0..15
    const int yt  = rem & 3;         // 0..3
    const int x0  = xt * TX;
    const int t   = threadIdx.x;

    for (int i = t; i < W_ * TX; i += 256) {
        int w = i >> 5, tx = i & 31;
        lonT[w][tx] = wlon[(b * W_ + w) * X_ + x0 + tx];
    }
    __syncthreads();

    const int tg = t >> 5, lg = t & 31;
    const int tx0 = tg * 4;
    const int h0  = lg * 8;

    float acc[8][4];
#pragma unroll
    for (int j = 0; j < 8; ++j)
#pragma unroll
        for (int i = 0; i < 4; ++i) acc[j][i] = 0.f;

    const float* wbase = wt + ((size_t)b * C_) * (size_t)(W_ * H_) + h0;  // channel 0
    for (int w = 0; w < W_; ++w) {
        float4 lv = *(const float4*)&lonT[w][tx0];
        const float* wr = wbase + (size_t)w * H_;
        float4 a0 = *(const float4*)wr;
        float4 a1 = *(const float4*)(wr + 4);
        float vv[8] = {a0.x, a0.y, a0.z, a0.w, a1.x, a1.y, a1.z, a1.w};
#pragma unroll
        for (int j = 0; j < 8; ++j) {
            float dv = (vv[j] != vv[j]) ? 0.f : 1.f;   // density: 1 where not NaN
            acc[j][0] += dv * lv.x;
            acc[j][1] += dv * lv.y;
            acc[j][2] += dv * lv.z;
            acc[j][3] += dv * lv.w;
        }
    }
#pragma unroll
    for (int j = 0; j < 8; ++j)
        *(float4*)&Tt[h0 + j][tx0] = make_float4(acc[j][0], acc[j][1], acc[j][2], acc[j][3]);
    __syncthreads();

    const int y0 = yt * 128 + lg * 4;
    float a2[4][4];
#pragma unroll
    for (int i = 0; i < 4; ++i)
#pragma unroll
        for (int j = 0; j < 4; ++j) a2[i][j] = 0.f;

    for (int h = 0; h < H_; ++h) {
        float4 tv = *(const float4*)&Tt[h][tx0];
        float4 wl = *(const float4*)&wlat[(size_t)(b * H_ + h) * Y_ + y0];
        float tvv[4] = {tv.x, tv.y, tv.z, tv.w};
        float wlv[4] = {wl.x, wl.y, wl.z, wl.w};
#pragma unroll
        for (int i = 0; i < 4; ++i)
#pragma unroll
            for (int j = 0; j < 4; ++j) a2[i][j] += tvv[i] * wlv[j];
    }

#pragma unroll
    for (int i = 0; i < 4; ++i) {
        int x = x0 + tx0 + i;
        float4 r = make_float4(a2[i][0], a2[i][1], a2[i][2], a2[i][3]);
        *(float4*)&ee0[((size_t)b * X_ + x) * Y_ + y0] = r;
        *(float4*)&out[(((size_t)b * CP) * X_ + x) * Y_ + y0] = r;
    }
}

// ---------------- data channels ----------------
// grid: 1024 blocks (B*C*(X/TX)), XCD-swizzled so all 16 x-tiles of one (b,c)
// land on one XCD (wt[b,c] panel = 256 KB stays L2-resident).
__global__ __launch_bounds__(256) void conv_kernel(
    const float* __restrict__ wt, const float* __restrict__ wlon,
    const float* __restrict__ wlat, const float* __restrict__ ee0,
    float* __restrict__ out)
{
    __shared__ float lonT[W_][TX];
    __shared__ float Tt[H_][TX];
    const int bid = blockIdx.x;
    const int xcd = bid & 7;
    const int idx = bid >> 3;        // 0..127
    const int g   = idx >> 4;        // 0..7
    const int xt  = idx & 15;        // 0..15
    const int bc  = xcd * 8 + g;     // 0..63
    const int b   = bc >> 5;
    const int c   = bc & 31;
    const int x0  = xt * TX;
    const int t   = threadIdx.x;

    for (int i = t; i < W_ * TX; i += 256) {
        int w = i >> 5, tx = i & 31;
        lonT[w][tx] = wlon[(b * W_ + w) * X_ + x0 + tx];
    }
    __syncthreads();

    const int tg = t >> 5, lg = t & 31;
    const int tx0 = tg * 4;
    const int h0  = lg * 8;

    float acc[8][4];
#pragma unroll
    for (int j = 0; j < 8; ++j)
#pragma unroll
        for (int i = 0; i < 4; ++i) acc[j][i] = 0.f;

    const float* wbase = wt + ((size_t)(b * C_ + c)) * (size_t)(W_ * H_) + h0;
    for (int w = 0; w < W_; ++w) {
        float4 lv = *(const float4*)&lonT[w][tx0];
        const float* wr = wbase + (size_t)w * H_;
        float4 a0 = *(const float4*)wr;
        float4 a1 = *(const float4*)(wr + 4);
        float vv[8] = {a0.x, a0.y, a0.z, a0.w, a1.x, a1.y, a1.z, a1.w};
#pragma unroll
        for (int j = 0; j < 8; ++j) {
            float v = (vv[j] != vv[j]) ? 0.f : vv[j];  // nan_to_num
            acc[j][0] += v * lv.x;
            acc[j][1] += v * lv.y;
            acc[j][2] += v * lv.z;
            acc[j][3] += v * lv.w;
        }
    }
#pragma unroll
    for (int j = 0; j < 8; ++j)
        *(float4*)&Tt[h0 + j][tx0] = make_float4(acc[j][0], acc[j][1], acc[j][2], acc[j][3]);
    __syncthreads();

    // stage 2: all Y=512; per-thread 4 tx x 16 y register tile
    const int y0 = lg * 16;
    float a2[4][16];
#pragma unroll
    for (int i = 0; i < 4; ++i)
#pragma unroll
        for (int j = 0; j < 16; ++j) a2[i][j] = 0.f;

    for (int h = 0; h < H_; ++h) {
        float4 tv = *(const float4*)&Tt[h][tx0];
        const float* wlp = &wlat[(size_t)(b * H_ + h) * Y_ + y0];
        float4 w0 = *(const float4*)(wlp);
        float4 w1 = *(const float4*)(wlp + 4);
        float4 w2 = *(const float4*)(wlp + 8);
        float4 w3 = *(const float4*)(wlp + 12);
        float tvv[4] = {tv.x, tv.y, tv.z, tv.w};
        float wlv[16] = {w0.x, w0.y, w0.z, w0.w, w1.x, w1.y, w1.z, w1.w,
                         w2.x, w2.y, w2.z, w2.w, w3.x, w3.y, w3.z, w3.w};
#pragma unroll
        for (int i = 0; i < 4; ++i)
#pragma unroll
            for (int j = 0; j < 16; ++j) a2[i][j] += tvv[i] * wlv[j];
    }

#pragma unroll
    for (int i = 0; i < 4; ++i) {
        int x = x0 + tx0 + i;
        const float* e0p = &ee0[((size_t)b * X_ + x) * Y_ + y0];
        float* op = &out[(((size_t)b * CP + 1 + c) * X_ + x) * Y_ + y0];
#pragma unroll
        for (int jj = 0; jj < 4; ++jj) {
            float4 e = *(const float4*)(e0p + jj * 4);
            float dx = fminf(fmaxf(e.x, 1e-6f), 1e5f);
            float dy = fminf(fmaxf(e.y, 1e-6f), 1e5f);
            float dz = fminf(fmaxf(e.z, 1e-6f), 1e5f);
            float dw = fminf(fmaxf(e.w, 1e-6f), 1e5f);
            float4 o = make_float4(a2[i][jj * 4 + 0] / dx,
                                   a2[i][jj * 4 + 1] / dy,
                                   a2[i][jj * 4 + 2] / dz,
                                   a2[i][jj * 4 + 3] / dw);
            *(float4*)(op + jj * 4) = o;
        }
    }
}

extern "C" void kernel_launch(void* const* d_in, const int* in_sizes, int n_in,
                              void* d_out, int out_size, void* d_ws, size_t ws_size,
                              hipStream_t stream)
{
    const float* xin_lon  = (const float*)d_in[0];
    const float* xin_lat  = (const float*)d_in[1];
    const float* wt       = (const float*)d_in[2];
    const float* xout_lon = (const float*)d_in[3];
    const float* xout_lat = (const float*)d_in[4];
    const float* init_ls  = (const float*)d_in[5];
    float* out  = (float*)d_out;
    float* ws   = (float*)d_ws;
    float* wlon = ws;                         // B*W*X
    float* wlat = wlon + B_ * W_ * X_;        // B*H*Y
    float* ee0  = wlat + B_ * H_ * Y_;        // B*X*Y

    rbf_kernel<<<2048, 256, 0, stream>>>(xin_lon, xin_lat, xout_lon, xout_lat,
                                         init_ls, wlon, wlat);
    dens_kernel<<<128, 256, 0, stream>>>(wt, wlon, wlat, ee0, out);
    conv_kernel<<<1024, 256, 0, stream>>>(wt, wlon, wlat, ee0, out);
}

// Round 2
// 104.767 us; speedup vs baseline: 4.0059x; 4.0059x over previous
//
#include <hip/hip_runtime.h>
#include <cstddef>

#define B_ 2
#define C_ 32
#define CP 33
#define W_ 256
#define H_ 256
#define X_ 512
#define Y_ 512
#define YT 32

typedef __bf16 bf16x8 __attribute__((ext_vector_type(8)));
typedef __bf16 bf16x4 __attribute__((ext_vector_type(4)));
typedef float  f32x4  __attribute__((ext_vector_type(4)));

// ws layout (bytes):
//   wlonT bf16 [B][X][W]      524288
//   wlatT bf16 [B][Y][H]      524288
//   wt33  bf16 [B][CP][W][H]  8650752   (ch0 = density, ch c = nan_to_num(wt[c-1]))
//   eeT0  f32  [B][Y][X]      2097152   (transposed density einsum result)
// total ~11.25 MB

// ---------------- prep: bf16 tables ----------------
__global__ __launch_bounds__(256) void prep_kernel(
    const float* __restrict__ xin_lon, const float* __restrict__ xin_lat,
    const float* __restrict__ xout_lon, const float* __restrict__ xout_lat,
    const float* __restrict__ init_ls, const float* __restrict__ wt,
    __bf16* __restrict__ wlonT, __bf16* __restrict__ wlatT,
    __bf16* __restrict__ wt33)
{
    const int NLON = B_ * X_ * W_;           // 262144
    const int NLAT = B_ * Y_ * H_;           // 262144
    int t = blockIdx.x * 256 + threadIdx.x;
    float ls = init_ls[0];
    float cc = -0.5f / (ls * ls);
    if (t < NLON) {
        int b = t / (X_ * W_);
        int r = t - b * (X_ * W_);
        int x = r >> 8;          // / W_
        int w = r & (W_ - 1);
        float d = xin_lon[b * W_ + w] - xout_lon[b * X_ + x];
        wlonT[t] = (__bf16)__expf(cc * d * d);
    } else if (t < NLON + NLAT) {
        int j = t - NLON;
        int b = j / (Y_ * H_);
        int r = j - b * (Y_ * H_);
        int y = r >> 8;          // / H_
        int h = r & (H_ - 1);
        float d = xin_lat[b * H_ + h] - xout_lat[b * Y_ + y];
        wlatT[j] = (__bf16)__expf(cc * d * d);
    } else {
        int j = t - (NLON + NLAT);           // 4 elems each
        int o = j * 4;
        int b = o / (CP * W_ * H_);
        int r = o - b * (CP * W_ * H_);
        int co = r / (W_ * H_);
        int p = r & (W_ * H_ - 1);
        float4 v;
        bf16x4 ov;
        if (co == 0) {
            v = *(const float4*)&wt[((size_t)b * C_) * (W_ * H_) + p];
            ov[0] = (__bf16)((v.x != v.x) ? 0.f : 1.f);
            ov[1] = (__bf16)((v.y != v.y) ? 0.f : 1.f);
            ov[2] = (__bf16)((v.z != v.z) ? 0.f : 1.f);
            ov[3] = (__bf16)((v.w != v.w) ? 0.f : 1.f);
        } else {
            v = *(const float4*)&wt[((size_t)b * C_ + (co - 1)) * (W_ * H_) + p];
            ov[0] = (__bf16)((v.x != v.x) ? 0.f : v.x);
            ov[1] = (__bf16)((v.y != v.y) ? 0.f : v.y);
            ov[2] = (__bf16)((v.z != v.z) ? 0.f : v.z);
            ov[3] = (__bf16)((v.w != v.w) ? 0.f : v.w);
        }
        *(bf16x4*)&wt33[o] = ov;
    }
}

// ---------------- fused two-stage MFMA contraction ----------------
// Per block: one (b, ch, y-tile of 32).
//   stage1: U[w=256][y=32]  = sum_h wt33[ch][w][h] * wlatT[y][h]
//   stage2: ee[x=512][y=32] = sum_w wlonT[x][w]   * U[w][y]
// B operands live in LDS in fragment-linear layout:
//   frag(kt, nt, lane) at [((kt*2+nt)*64 + lane)*8], lane = ((k>>3)&3)*16 + n
template<bool DENS>
__global__ __launch_bounds__(256) void conv_mfma(
    const __bf16* __restrict__ wt33, const __bf16* __restrict__ wlonT,
    const __bf16* __restrict__ wlatT, float* __restrict__ eeT0,
    float* __restrict__ out)
{
    __shared__ __bf16 Blat[8192];   // 16 KB
    __shared__ __bf16 Ut[8192];     // 16 KB

    int b, ch, yt;
    if (DENS) {
        b  = blockIdx.x >> 4;
        yt = blockIdx.x & 15;
        ch = 0;
    } else {
        int xcd = blockIdx.x & 7;        // 16 y-tiles of one (b,c) share an XCD
        int idx = blockIdx.x >> 3;
        int g   = idx >> 4;
        yt      = idx & 15;
        int bc  = xcd * 8 + g;
        b  = bc >> 5;
        ch = (bc & 31) + 1;
    }
    const int y0   = yt * YT;
    const int t    = threadIdx.x;
    const int lane = t & 63;
    const int wave = t >> 6;
    const int lrow = lane & 15;
    const int lkg  = lane >> 4;

    // ---- stage wlatT y-tile into LDS (fragment-linear) ----
    {
        const __bf16* src = wlatT + ((size_t)b * Y_ + y0) * H_;
        int i = t;                        // 1024 chunks of 16B
#pragma unroll
        for (int it = 0; it < 4; ++it, i += 256) {
            int y = i >> 5, hc = i & 31;  // h0 = hc*8
            bf16x8 v = *(const bf16x8*)(src + y * H_ + hc * 8);
            int kt = hc >> 2, kg = hc & 3, nt = y >> 4;
            *(bf16x8*)&Blat[(((kt * 2 + nt) * 64) + kg * 16 + (y & 15)) * 8] = v;
        }
    }
    __syncthreads();

    // ---- stage 1 ----
    const __bf16* wtc = wt33 + ((size_t)b * CP + ch) * (W_ * H_);
    f32x4 acc1[4][2] = {};
    for (int kt = 0; kt < 8; ++kt) {
        bf16x8 a[4];
#pragma unroll
        for (int mt = 0; mt < 4; ++mt) {
            int w = wave * 64 + mt * 16 + lrow;
            a[mt] = *(const bf16x8*)(wtc + (size_t)w * H_ + kt * 32 + lkg * 8);
        }
        bf16x8 bf[2];
#pragma unroll
        for (int nt = 0; nt < 2; ++nt)
            bf[nt] = *(const bf16x8*)&Blat[((kt * 2 + nt) * 64 + lane) * 8];
#pragma unroll
        for (int mt = 0; mt < 4; ++mt)
#pragma unroll
            for (int nt = 0; nt < 2; ++nt)
                acc1[mt][nt] = __builtin_amdgcn_mfma_f32_16x16x32_bf16(
                    a[mt], bf[nt], acc1[mt][nt], 0, 0, 0);
    }

    // ---- U -> LDS, transposed into stage-2 fragment-linear layout ----
    // C layout: col = lane&15 (y), rows = lkg*4 + r (w), 4 consecutive w.
#pragma unroll
    for (int mt = 0; mt < 4; ++mt) {
        int w0  = wave * 64 + mt * 16 + lkg * 4;
        int kt2 = w0 >> 5;
        int kg2 = (w0 >> 3) & 3;
        int j0  = w0 & 7;                 // 0 or 4
#pragma unroll
        for (int nt = 0; nt < 2; ++nt) {
            f32x4 c = acc1[mt][nt];
            bf16x4 v4;
            v4[0] = (__bf16)c[0]; v4[1] = (__bf16)c[1];
            v4[2] = (__bf16)c[2]; v4[3] = (__bf16)c[3];
            *(bf16x4*)&Ut[((kt2 * 2 + nt) * 64 + kg2 * 16 + lrow) * 8 + j0] = v4;
        }
    }
    __syncthreads();

    // ---- stage 2 ----
    f32x4 acc2[8][2] = {};
    const __bf16* lonb = wlonT + (size_t)b * X_ * W_;
    for (int kt = 0; kt < 8; ++kt) {
        bf16x8 bf[2];
#pragma unroll
        for (int nt = 0; nt < 2; ++nt)
            bf[nt] = *(const bf16x8*)&Ut[((kt * 2 + nt) * 64 + lane) * 8];
#pragma unroll
        for (int mt = 0; mt < 8; ++mt) {
            int x = wave * 128 + mt * 16 + lrow;
            bf16x8 a = *(const bf16x8*)(lonb + (size_t)x * W_ + kt * 32 + lkg * 8);
#pragma unroll
            for (int nt = 0; nt < 2; ++nt)
                acc2[mt][nt] = __builtin_amdgcn_mfma_f32_16x16x32_bf16(
                    a, bf[nt], acc2[mt][nt], 0, 0, 0);
        }
    }

    // ---- epilogue ----
    float* outc = out + ((size_t)b * CP + ch) * (size_t)(X_ * Y_);
#pragma unroll
    for (int mt = 0; mt < 8; ++mt) {
        int xb = wave * 128 + mt * 16 + lkg * 4;
#pragma unroll
        for (int nt = 0; nt < 2; ++nt) {
            int y = y0 + nt * 16 + lrow;
            f32x4 c = acc2[mt][nt];
            if (DENS) {
                *(f32x4*)&eeT0[((size_t)b * Y_ + y) * X_ + xb] = c;
#pragma unroll
                for (int r = 0; r < 4; ++r)
                    outc[(size_t)(xb + r) * Y_ + y] = c[r];
            } else {
                f32x4 e = *(const f32x4*)&eeT0[((size_t)b * Y_ + y) * X_ + xb];
#pragma unroll
                for (int r = 0; r < 4; ++r) {
                    float dcl = fminf(fmaxf(e[r], 1e-6f), 1e5f);
                    outc[(size_t)(xb + r) * Y_ + y] = c[r] / dcl;
                }
            }
        }
    }
}

extern "C" void kernel_launch(void* const* d_in, const int* in_sizes, int n_in,
                              void* d_out, int out_size, void* d_ws, size_t ws_size,
                              hipStream_t stream)
{
    const float* xin_lon  = (const float*)d_in[0];
    const float* xin_lat  = (const float*)d_in[1];
    const float* wt       = (const float*)d_in[2];
    const float* xout_lon = (const float*)d_in[3];
    const float* xout_lat = (const float*)d_in[4];
    const float* init_ls  = (const float*)d_in[5];
    float* out = (float*)d_out;

    __bf16* wlonT = (__bf16*)d_ws;                         // B*X*W
    __bf16* wlatT = wlonT + (size_t)B_ * X_ * W_;          // B*Y*H
    __bf16* wt33  = wlatT + (size_t)B_ * Y_ * H_;          // B*CP*W*H
    float*  eeT0  = (float*)(wt33 + (size_t)B_ * CP * W_ * H_);  // B*Y*X

    // 262144 + 262144 + 1081344 threads = 6272 blocks * 256
    prep_kernel<<<6272, 256, 0, stream>>>(xin_lon, xin_lat, xout_lon, xout_lat,
                                          init_ls, wt, wlonT, wlatT, wt33);
    conv_mfma<true ><<<32,   256, 0, stream>>>(wt33, wlonT, wlatT, eeT0, out);
    conv_mfma<false><<<1024, 256, 0, stream>>>(wt33, wlonT, wlatT, eeT0, out);
}

// Round 3
// 79.400 us; speedup vs baseline: 5.2856x; 1.3195x over previous
//
#include <hip/hip_runtime.h>
#include <cstddef>

#define B_ 2
#define C_ 32
#define CP 33
#define W_ 256
#define H_ 256
#define X_ 512
#define Y_ 512
#define YT 32

typedef __bf16 bf16x8 __attribute__((ext_vector_type(8)));
typedef __bf16 bf16x4 __attribute__((ext_vector_type(4)));
typedef float  f32x4  __attribute__((ext_vector_type(4)));

// ws layout:
//   wlonT bf16 [B][X][W], wlatT bf16 [B][Y][H], wt33 bf16 [B][CP][W][H],
//   eeT0 f32 [B][Y][X]

// ---------------- prep: bf16 tables ----------------
__global__ __launch_bounds__(256) void prep_kernel(
    const float* __restrict__ xin_lon, const float* __restrict__ xin_lat,
    const float* __restrict__ xout_lon, const float* __restrict__ xout_lat,
    const float* __restrict__ init_ls, const float* __restrict__ wt,
    __bf16* __restrict__ wlonT, __bf16* __restrict__ wlatT,
    __bf16* __restrict__ wt33)
{
    const int NLON = B_ * X_ * W_;
    const int NLAT = B_ * Y_ * H_;
    int t = blockIdx.x * 256 + threadIdx.x;
    float ls = init_ls[0];
    float cc = -0.5f / (ls * ls);
    if (t < NLON) {
        int b = t / (X_ * W_);
        int r = t - b * (X_ * W_);
        int x = r >> 8;
        int w = r & (W_ - 1);
        float d = xin_lon[b * W_ + w] - xout_lon[b * X_ + x];
        wlonT[t] = (__bf16)__expf(cc * d * d);
    } else if (t < NLON + NLAT) {
        int j = t - NLON;
        int b = j / (Y_ * H_);
        int r = j - b * (Y_ * H_);
        int y = r >> 8;
        int h = r & (H_ - 1);
        float d = xin_lat[b * H_ + h] - xout_lat[b * Y_ + y];
        wlatT[j] = (__bf16)__expf(cc * d * d);
    } else {
        int j = t - (NLON + NLAT);
        int o = j * 4;
        int b = o / (CP * W_ * H_);
        int r = o - b * (CP * W_ * H_);
        int co = r / (W_ * H_);
        int p = r & (W_ * H_ - 1);
        float4 v;
        bf16x4 ov;
        if (co == 0) {
            v = *(const float4*)&wt[((size_t)b * C_) * (W_ * H_) + p];
            ov[0] = (__bf16)((v.x != v.x) ? 0.f : 1.f);
            ov[1] = (__bf16)((v.y != v.y) ? 0.f : 1.f);
            ov[2] = (__bf16)((v.z != v.z) ? 0.f : 1.f);
            ov[3] = (__bf16)((v.w != v.w) ? 0.f : 1.f);
        } else {
            v = *(const float4*)&wt[((size_t)b * C_ + (co - 1)) * (W_ * H_) + p];
            ov[0] = (__bf16)((v.x != v.x) ? 0.f : v.x);
            ov[1] = (__bf16)((v.y != v.y) ? 0.f : v.y);
            ov[2] = (__bf16)((v.z != v.z) ? 0.f : v.z);
            ov[3] = (__bf16)((v.w != v.w) ? 0.f : v.w);
        }
        *(bf16x4*)&wt33[o] = ov;
    }
}

// ---------------- fused two-stage MFMA contraction ----------------
// stage1: U[w=256][y=32]  = sum_h wt33[ch][w][h] * wlatT[y][h]
// stage2: ee[x-chunk][y=32] = sum_w wlonT[x][w] * U[w][y]
// NXQ = x-split factor (1 for main, 4 for density pass).
template<int NXQ, bool DENS>
__global__ __launch_bounds__(256, 4) void conv_mfma(
    const __bf16* __restrict__ wt33, const __bf16* __restrict__ wlonT,
    const __bf16* __restrict__ wlatT, float* __restrict__ eeT0,
    float* __restrict__ out)
{
    constexpr int XCH = X_ / NXQ;    // x per block
    constexpr int MT  = XCH / 64;    // stage-2 m-fragments per wave
    constexpr int HM  = MT / 2;

    __shared__ __bf16 Blat[8192];
    __shared__ __bf16 Ut[8192];

    int b, ch, yt, xq;
    if (DENS) {
        b  = blockIdx.x / (16 * NXQ);
        int r = blockIdx.x - b * (16 * NXQ);
        yt = r / NXQ;
        xq = r - yt * NXQ;
        ch = 0;
    } else {
        int xcd = blockIdx.x & 7;
        int idx = blockIdx.x >> 3;
        int g   = idx >> 4;
        yt      = idx & 15;
        int bc  = xcd * 8 + g;
        b  = bc >> 5;
        ch = (bc & 31) + 1;
        xq = 0;
    }
    const int y0   = yt * YT;
    const int t    = threadIdx.x;
    const int lane = t & 63;
    const int wave = t >> 6;
    const int lrow = lane & 15;
    const int lkg  = lane >> 4;

    // ---- stage wlatT y-tile into LDS (fragment-linear) ----
    {
        const __bf16* src = wlatT + ((size_t)b * Y_ + y0) * H_;
        int i = t;
#pragma unroll
        for (int it = 0; it < 4; ++it, i += 256) {
            int y = i >> 5, hc = i & 31;
            bf16x8 v = *(const bf16x8*)(src + y * H_ + hc * 8);
            int kt = hc >> 2, kg = hc & 3, nt = y >> 4;
            *(bf16x8*)&Blat[(((kt * 2 + nt) * 64) + kg * 16 + (y & 15)) * 8] = v;
        }
    }
    __syncthreads();

    // ---- stage 1 (software-pipelined over kt) ----
    const __bf16* wtc = wt33 + ((size_t)b * CP + ch) * (W_ * H_);
    auto loadA1 = [&](bf16x8* a, int kt) {
#pragma unroll
        for (int mt = 0; mt < 4; ++mt) {
            int w = wave * 64 + mt * 16 + lrow;
            a[mt] = *(const bf16x8*)(wtc + (size_t)w * H_ + kt * 32 + lkg * 8);
        }
    };
    f32x4 acc1[4][2] = {};
    bf16x8 aA[4], aB[4];
    loadA1(aA, 0);
#pragma unroll
    for (int kt = 0; kt < 8; ++kt) {
        bf16x8* ac = (kt & 1) ? aB : aA;
        bf16x8* an = (kt & 1) ? aA : aB;
        if (kt < 7) loadA1(an, kt + 1);
        bf16x8 bf[2];
#pragma unroll
        for (int nt = 0; nt < 2; ++nt)
            bf[nt] = *(const bf16x8*)&Blat[((kt * 2 + nt) * 64 + lane) * 8];
#pragma unroll
        for (int mt = 0; mt < 4; ++mt)
#pragma unroll
            for (int nt = 0; nt < 2; ++nt)
                acc1[mt][nt] = __builtin_amdgcn_mfma_f32_16x16x32_bf16(
                    ac[mt], bf[nt], acc1[mt][nt], 0, 0, 0);
    }

    // ---- issue stage-2 first A-group before publishing Ut ----
    const __bf16* lonb = wlonT + (size_t)b * X_ * W_;
    auto loadA2 = [&](bf16x8* a, int kt, int half) {
#pragma unroll
        for (int i = 0; i < HM; ++i) {
            int mt = half * HM + i;
            int x  = xq * XCH + wave * (XCH / 4) + mt * 16 + lrow;
            a[i] = *(const bf16x8*)(lonb + (size_t)x * W_ + kt * 32 + lkg * 8);
        }
    };
    bf16x8 g0[HM], g1[HM];
    loadA2(g0, 0, 0);
    loadA2(g1, 0, 1);

    // ---- U -> LDS (stage-2 fragment-linear, transposed) ----
#pragma unroll
    for (int mt = 0; mt < 4; ++mt) {
        int w0  = wave * 64 + mt * 16 + lkg * 4;
        int kt2 = w0 >> 5;
        int kg2 = (w0 >> 3) & 3;
        int j0  = w0 & 7;
#pragma unroll
        for (int nt = 0; nt < 2; ++nt) {
            f32x4 c = acc1[mt][nt];
            bf16x4 v4;
            v4[0] = (__bf16)c[0]; v4[1] = (__bf16)c[1];
            v4[2] = (__bf16)c[2]; v4[3] = (__bf16)c[3];
            *(bf16x4*)&Ut[((kt2 * 2 + nt) * 64 + kg2 * 16 + lrow) * 8 + j0] = v4;
        }
    }
    __syncthreads();

    // ---- stage 2 (software-pipelined: half-group granularity) ----
    f32x4 acc2[MT][2] = {};
#pragma unroll
    for (int kt = 0; kt < 8; ++kt) {
        bf16x8 bf[2];
#pragma unroll
        for (int nt = 0; nt < 2; ++nt)
            bf[nt] = *(const bf16x8*)&Ut[((kt * 2 + nt) * 64 + lane) * 8];
#pragma unroll
        for (int i = 0; i < HM; ++i)
#pragma unroll
            for (int nt = 0; nt < 2; ++nt)
                acc2[i][nt] = __builtin_amdgcn_mfma_f32_16x16x32_bf16(
                    g0[i], bf[nt], acc2[i][nt], 0, 0, 0);
        if (kt < 7) loadA2(g0, kt + 1, 0);
#pragma unroll
        for (int i = 0; i < HM; ++i)
#pragma unroll
            for (int nt = 0; nt < 2; ++nt)
                acc2[HM + i][nt] = __builtin_amdgcn_mfma_f32_16x16x32_bf16(
                    g1[i], bf[nt], acc2[HM + i][nt], 0, 0, 0);
        if (kt < 7) loadA2(g1, kt + 1, 1);
    }

    // ---- epilogue ----
    float* outc = out + ((size_t)b * CP + ch) * (size_t)(X_ * Y_);
#pragma unroll
    for (int mt = 0; mt < MT; ++mt) {
        int xb = xq * XCH + wave * (XCH / 4) + mt * 16 + lkg * 4;
#pragma unroll
        for (int nt = 0; nt < 2; ++nt) {
            int y = y0 + nt * 16 + lrow;
            f32x4 c = acc2[mt][nt];
            if (DENS) {
                *(f32x4*)&eeT0[((size_t)b * Y_ + y) * X_ + xb] = c;
#pragma unroll
                for (int r = 0; r < 4; ++r)
                    outc[(size_t)(xb + r) * Y_ + y] = c[r];
            } else {
                f32x4 e = *(const f32x4*)&eeT0[((size_t)b * Y_ + y) * X_ + xb];
#pragma unroll
                for (int r = 0; r < 4; ++r) {
                    float dcl = fminf(fmaxf(e[r], 1e-6f), 1e5f);
                    outc[(size_t)(xb + r) * Y_ + y] = c[r] / dcl;
                }
            }
        }
    }
}

extern "C" void kernel_launch(void* const* d_in, const int* in_sizes, int n_in,
                              void* d_out, int out_size, void* d_ws, size_t ws_size,
                              hipStream_t stream)
{
    const float* xin_lon  = (const float*)d_in[0];
    const float* xin_lat  = (const float*)d_in[1];
    const float* wt       = (const float*)d_in[2];
    const float* xout_lon = (const float*)d_in[3];
    const float* xout_lat = (const float*)d_in[4];
    const float* init_ls  = (const float*)d_in[5];
    float* out = (float*)d_out;

    __bf16* wlonT = (__bf16*)d_ws;
    __bf16* wlatT = wlonT + (size_t)B_ * X_ * W_;
    __bf16* wt33  = wlatT + (size_t)B_ * Y_ * H_;
    float*  eeT0  = (float*)(wt33 + (size_t)B_ * CP * W_ * H_);

    prep_kernel<<<6272, 256, 0, stream>>>(xin_lon, xin_lat, xout_lon, xout_lat,
                                          init_ls, wt, wlonT, wlatT, wt33);
    conv_mfma<4, true ><<<B_ * 16 * 4, 256, 0, stream>>>(wt33, wlonT, wlatT, eeT0, out);
    conv_mfma<1, false><<<1024,        256, 0, stream>>>(wt33, wlonT, wlatT, eeT0, out);
}